// Round 9
// baseline (131.515 us; speedup 1.0000x reference)
//
#include <hip/hip_runtime.h>

#define BB 8
#define CC 512
#define NH 8
#define HH 96
#define WW 96
#define PLANE (HH*WW)        // 9216
#define NPLANE (NH*PLANE)    // 73728
#define TROWS 8              // query rows per block
#define TCOLS 16             // query cols per block (= MFMA M)
#define KROWS 14             // staged key rows: h0-3 .. h0+10
#define KCOLS 36             // staged key cols: w0-4 .. w0+31 (16B-aligned halo)
#define NTHR 256

typedef float  f4    __attribute__((ext_vector_type(4), may_alias));
typedef _Float16 f16x8 __attribute__((ext_vector_type(8), may_alias));
typedef float  f32x4 __attribute__((ext_vector_type(4), may_alias));
typedef decltype(__builtin_amdgcn_cvt_pkrtz(0.f, 0.f)) h2;

union F8 { f16x8 v; h2 h[4]; f32x4 f; };

// Per-wave: 2 query rows; B-frag (key row y, 16 cols, k-slice) shared by both
// rows as offsets i=it and i=it-1 -> 32 ds_read_b128 feed 56 MFMAs.
__global__ __launch_bounds__(NTHR, 2)
void mov_kernel(const float* __restrict__ qin, const float* __restrict__ kin,
                float* __restrict__ out)
{
    const int tid = threadIdx.x;
    const int bid = blockIdx.x;
    // XCD-aware: all 72 tiles of one (b, head) slice share one XCD (bid & 7)
    const int n  = bid & 7;
    const int t2 = bid >> 3;            // 0..575
    const int b  = t2 / 72;
    const int tt = t2 - b * 72;
    const int h0 = (tt / 6) * TROWS;
    const int w0 = (tt % 6) * TCOLS;

    const int lane = tid & 63;
    const int wv   = tid >> 6;          // wave 0..3: rows h0+2wv, h0+2wv+1
    const int g    = lane >> 4;         // k-group 0..3
    const int mm   = lane & 15;         // M-row (A) / N-col (B)

    __shared__ float smem[KROWS * KCOLS * 32];   // 64512 B; k-tile, then logits

    // ---------- A fragments: q direct from global (no block-level reuse) ----------
    // A[m][k]: lane holds m = lane&15, k = (lane>>4)*8 + e (e contiguous in d)
    const int h_a = h0 + 2 * wv;
    f16x8 A[2][2];                       // [row][kstep]
#pragma unroll
    for (int rr = 0; rr < 2; ++rr)
#pragma unroll
        for (int ks = 0; ks < 2; ++ks) {
            float v[8];
#pragma unroll
            for (int e = 0; e < 8; ++e) {
                int d = ks * 32 + g * 8 + e;
                v[e] = qin[(b * CC + d * NH + n) * PLANE + (h_a + rr) * WW + w0 + mm] * 0.125f;
            }
            F8 u;
#pragma unroll
            for (int p = 0; p < 4; ++p)
                u.h[p] = __builtin_amdgcn_cvt_pkrtz(v[2 * p], v[2 * p + 1]);
            A[rr][ks] = u.v;
        }

    // ---------- stage k tile: [y][c][slot8]x16B, slot = dgrp ^ (c&7) ----------
    // task t: dg = t&7 (fastest -> per-instr 8 planes x 128B coalesced global,
    // and the 8 dg-lanes of one (y,cu) write 8 swizzled slots = 128B: conflict-free)
    {
        const int kb = (b * CC + n) * PLANE;
#pragma unroll
        for (int s = 0; s < 4; ++s) {
            int t = tid + s * NTHR;
            if (t < 1008) {                       // 14y * 9cu * 8dg
                int dg = t & 7;
                int u2 = t >> 3;                  // 0..125
                int cu = u2 % 9;
                int y  = u2 / 9;                  // 0..13
                int yg = min(max(h0 - 3 + y, 0), HH - 1);
                int cg = min(max(w0 - 4 + 4 * cu, 0), WW - 4);   // 16B-aligned
                const float* kp = kin + kb + dg * 8 * NPLANE + yg * WW + cg;
                f4 v[8];
#pragma unroll
                for (int e = 0; e < 8; ++e)
                    v[e] = *(const f4*)(kp + e * NPLANE);
#pragma unroll
                for (int cc = 0; cc < 4; ++cc) {
                    F8 u;
#pragma unroll
                    for (int p = 0; p < 4; ++p)
                        u.h[p] = __builtin_amdgcn_cvt_pkrtz(v[2 * p][cc], v[2 * p + 1][cc]);
                    int c = cu * 4 + cc;
                    ((f32x4*)smem)[(y * KCOLS + c) * 8 + (dg ^ (c & 7))] = u.f;
                }
            }
        }
    }
    __syncthreads();

    // ---------- band MFMA: 2 ksteps x 8 key rows, B shared by both acc rows ----------
    f32x4 acc[2][7][2];
#pragma unroll
    for (int rr = 0; rr < 2; ++rr)
#pragma unroll
        for (int i = 0; i < 7; ++i)
#pragma unroll
            for (int nt = 0; nt < 2; ++nt)
                acc[rr][i][nt] = (f32x4){0.f, 0.f, 0.f, 0.f};

#pragma unroll
    for (int ks = 0; ks < 2; ++ks) {
#pragma unroll
        for (int it = 0; it < 8; ++it) {
            int yl = 2 * wv + it;                 // staged row (global y = h_a-3+it)
            int c0 = 1 + mm;                      // N-tile0: global col w0-3+n
            int c1 = 17 + mm;                     // N-tile1: global col w0+13+n
            F8 b0, b1;
            b0.f = ((const f32x4*)smem)[(yl * KCOLS + c0) * 8 + ((ks * 4 + g) ^ (c0 & 7))];
            b1.f = ((const f32x4*)smem)[(yl * KCOLS + c1) * 8 + ((ks * 4 + g) ^ (c1 & 7))];
            if (it < 7) {   // row a: i = it
                acc[0][it][0] = __builtin_amdgcn_mfma_f32_16x16x32_f16(A[0][ks], b0.v, acc[0][it][0], 0, 0, 0);
                acc[0][it][1] = __builtin_amdgcn_mfma_f32_16x16x32_f16(A[0][ks], b1.v, acc[0][it][1], 0, 0, 0);
            }
            if (it > 0) {   // row b: i = it-1
                acc[1][it - 1][0] = __builtin_amdgcn_mfma_f32_16x16x32_f16(A[1][ks], b0.v, acc[1][it - 1][0], 0, 0, 0);
                acc[1][it - 1][1] = __builtin_amdgcn_mfma_f32_16x16x32_f16(A[1][ks], b1.v, acc[1][it - 1][1], 0, 0, 0);
            }
        }
    }
    __syncthreads();   // all waves done reading k before logits overwrite it

    // ---------- scatter band entries: D[m][n] -> lb[px][o], o = i*7+j ----------
    // C/D layout: n = lane&15, m = (lane>>4)*4 + reg (m89-verified family)
    float* lb = smem + wv * 1664;                 // [32 px][52] f32 per wave
#pragma unroll
    for (int rr = 0; rr < 2; ++rr)
#pragma unroll
        for (int i = 0; i < 7; ++i)
#pragma unroll
            for (int nt = 0; nt < 2; ++nt)
#pragma unroll
                for (int qq = 0; qq < 4; ++qq) {
                    int m = g * 4 + qq;
                    int j = nt * 16 + mm - m;     // key col - pixel col + 3
                    if ((unsigned)j < 7u)
                        lb[(rr * 16 + m) * 52 + i * 7 + j] = acc[rr][i][nt][qq];
                }

    // ---------- gather + softmax over 49 offsets + expectation ----------
    const int pxl = lane & 31;
    const int rr2 = pxl >> 4, m2 = pxl & 15;
    const int ih  = lane >> 5;                    // o-half: 0..27 / 28..55
    const int hp  = h0 + 2 * wv + rr2;
    const int wp  = w0 + m2;

    const float* pr = lb + pxl * 52 + ih * 28;
    float vals[28];
#pragma unroll
    for (int vq = 0; vq < 7; ++vq) {
        if (vq < 7 - ih) {                        // ih=1 reads only 6 vecs (o<=51)
            f4 tv = *(const f4*)(pr + vq * 4);
#pragma unroll
            for (int e = 0; e < 4; ++e) vals[vq * 4 + e] = tv[e];
        } else {
#pragma unroll
            for (int e = 0; e < 4; ++e) vals[vq * 4 + e] = -1e30f;
        }
    }
    // mask invalid offsets: o = ih*28 + t, i = ih*4 + t/7, j = t%7
#pragma unroll
    for (int t = 0; t < 28; ++t) {
        const int ii = t / 7, j = t % 7;
        int i = ih * 4 + ii;
        bool ok = (i < 7)
               && ((unsigned)(hp + i - 3) < (unsigned)HH)
               && ((unsigned)(wp + j - 3) < (unsigned)WW);
        if (!ok) vals[t] = -1e30f;
    }

    float mh = -1e30f;
#pragma unroll
    for (int t = 0; t < 28; ++t) mh = fmaxf(mh, vals[t]);
    float mt = fmaxf(mh, __shfl_xor(mh, 32));

    float l = 0.f, di = 0.f, dj = 0.f;
#pragma unroll
    for (int t = 0; t < 28; ++t) {
        const int ii = t / 7, j = t % 7;
        float e = __expf(vals[t] - mt);
        l  += e;
        di += e * (float)(ih * 4 + ii - 3);
        dj += e * (float)(j - 3);
    }
    l  += __shfl_xor(l, 32);
    di += __shfl_xor(di, 32);
    dj += __shfl_xor(dj, 32);

    if (lane < 32) {
        float inv = 1.0f / (l * (float)NH);       // softmax denom * head-mean /8
        atomicAdd(out + (b * 2 + 0) * PLANE + hp * WW + wp, di * inv);
        atomicAdd(out + (b * 2 + 1) * PLANE + hp * WW + wp, dj * inv);
    }
}

extern "C" void kernel_launch(void* const* d_in, const int* in_sizes, int n_in,
                              void* d_out, int out_size, void* d_ws, size_t ws_size,
                              hipStream_t stream) {
    const float* q = (const float*)d_in[0];
    const float* k = (const float*)d_in[1];
    float* out = (float*)d_out;

    hipMemsetAsync(out, 0, (size_t)out_size * sizeof(float), stream);

    dim3 grid(BB * NH * (HH / TROWS) * (WW / TCOLS));   // 4608
    dim3 block(NTHR);
    hipLaunchKernelGGL(mov_kernel, grid, block, 0, stream, q, k, out);
}